// Round 8
// baseline (148.755 us; speedup 1.0000x reference)
//
#include <hip/hip_runtime.h>
#include <hip/hip_cooperative_groups.h>
#include <math.h>

namespace cg = cooperative_groups;

#define Bdim 64
#define Tdim 512
#define Sdim 400
#define Hdim 768
#define Ldim 9
#define PSTRIDE 12

#define NBLK 256   // one block per CU; cooperative co-residency guaranteed
#define NTHR 256   // 4 waves
#define SLOTS 128  // tokens per block in phase 2 (256*128 = 32768 = B*T)
#define WPB 100    // words per block in phase 3 (256*100 = 25600 = B*S)

// ---------------------------------------------------------------------------
// DPP 64-lane sum (row_shr 1/2/4/8 + row_bcast 15/31), result in lane 63.
// Pure VALU, no DS pipe.
// ---------------------------------------------------------------------------
template <int CTRL>
__device__ __forceinline__ float dpp_add(float x) {
  int y = __builtin_amdgcn_update_dpp(0, __float_as_int(x), CTRL, 0xF, 0xF, false);
  return x + __int_as_float(y);
}
__device__ __forceinline__ float wave_sum63(float x) {
  x = dpp_add<0x111>(x);
  x = dpp_add<0x112>(x);
  x = dpp_add<0x114>(x);
  x = dpp_add<0x118>(x);
  x = dpp_add<0x142>(x);
  x = dpp_add<0x143>(x);
  return x;  // lane 63 = sum of all 64 lanes
}

// ---------------------------------------------------------------------------
// Single fused cooperative kernel:
//  phase 1 (blocks 0..63): per-row scans -> pos2tok / wstart / nvalid
//  phase 2 (all blocks):   proj[b,q,:] = enc[b,pos2tok[b,q],:] @ W
//                          L-split 3/2/2/2 over 4 waves (wf <= 12 floats/lane;
//                          R5 showed 108-float fragments get rematerialized)
//  phase 3 (all blocks):   100 words/block: mean, +bias, argmax, NLL partials
//  phase 4 (block 0):      reduce 256 partials -> loss
// ---------------------------------------------------------------------------
__global__ __launch_bounds__(NTHR, 1) void fused_kernel(
    const float* __restrict__ enc, const float* __restrict__ W,
    const float* __restrict__ bias, const int* __restrict__ attn,
    const int* __restrict__ ids_lens, const int* __restrict__ label_ids,
    int* __restrict__ pos2tok, int* __restrict__ wstart,
    int* __restrict__ nvalid, float* __restrict__ proj,
    float2* __restrict__ partials, float* __restrict__ out) {
  cg::grid_group grid = cg::this_grid();
  int blk = blockIdx.x, tid = threadIdx.x;
  int lane = tid & 63, w = tid >> 6;
  __shared__ int wsum[4];
  __shared__ int tot;
  __shared__ float ssm[4], csm[4];

  // ================= phase 1: per-row scans (blocks 0..63) =================
  if (blk < Bdim) {
    int b = blk;
    // ---- attn scan: 512 elements, 2 per thread ----
    int a0 = attn[b * Tdim + 2 * tid];
    int a1 = attn[b * Tdim + 2 * tid + 1];
    int pr = a0 + a1, x = pr;
#pragma unroll
    for (int off = 1; off < 64; off <<= 1) {
      int v = __shfl_up(x, off, 64);
      if (lane >= off) x += v;
    }
    if (lane == 63) wsum[w] = x;
    __syncthreads();
    if (tid < 4) {
      int s = wsum[tid], y = s;
#pragma unroll
      for (int off = 1; off < 4; off <<= 1) {
        int v = __shfl_up(y, off, 64);
        if (tid >= off) y += v;
      }
      wsum[tid] = y - s;
      if (tid == 3) tot = y;
    }
    __syncthreads();
    int excl = x + wsum[w] - pr;  // exclusive prefix before elem 2*tid
    if (a0) pos2tok[b * Tdim + excl + a0 - 1] = 2 * tid;
    if (a1) pos2tok[b * Tdim + excl + a0 + a1 - 1] = 2 * tid + 1;
    if (tid == 0) nvalid[b] = tot;
    __syncthreads();
    // ---- ids_lens scan: 400 elements (pad to 512) ----
    int e0 = (2 * tid < Sdim) ? ids_lens[b * Sdim + 2 * tid] : 0;
    int e1 = (2 * tid + 1 < Sdim) ? ids_lens[b * Sdim + 2 * tid + 1] : 0;
    int pr2 = e0 + e1, x2 = pr2;
#pragma unroll
    for (int off = 1; off < 64; off <<= 1) {
      int v = __shfl_up(x2, off, 64);
      if (lane >= off) x2 += v;
    }
    if (lane == 63) wsum[w] = x2;
    __syncthreads();
    if (tid < 4) {
      int s = wsum[tid], y = s;
#pragma unroll
      for (int off = 1; off < 4; off <<= 1) {
        int v = __shfl_up(y, off, 64);
        if (tid >= off) y += v;
      }
      wsum[tid] = y - s;
    }
    __syncthreads();
    int excl2 = x2 + wsum[w] - pr2;
    if (2 * tid < Sdim) wstart[b * Sdim + 2 * tid] = excl2;
    if (2 * tid + 1 < Sdim) wstart[b * Sdim + 2 * tid + 1] = excl2 + e0;
  }
  grid.sync();

  // ================= phase 2: token projection (all blocks) ================
  {
    int base = blk * SLOTS;
    int b = base >> 9, q0 = base & 511;  // Tdim == 512
    int vc = nvalid[b] - q0;
    vc = vc < 0 ? 0 : (vc > SLOTS ? SLOTS : vc);
    if (vc > 0) {  // block-uniform
      int l0 = (w == 0) ? 0 : (1 + 2 * w);  // 0,3,5,7
      int nc = (w == 0) ? 3 : 2;            // logit count for this wave
      float wf[3][4][3];
#pragma unroll
      for (int k = 0; k < 3; ++k)
#pragma unroll
        for (int j = 0; j < 4; ++j) {
          int h = 4 * lane + 256 * k + j;
#pragma unroll
          for (int c = 0; c < 3; ++c)
            if (c < nc) wf[k][j][c] = W[(size_t)h * Ldim + l0 + c];
        }
      const float4* encb = (const float4*)enc + (size_t)(b << 9) * (Hdim / 4);

      float4 xa0, xa1, xa2, xb0, xb1, xb2;
#define LDROW(v0, v1, v2, IDX)                                   \
      {                                                          \
        int ii = (IDX) < vc ? (IDX) : (vc - 1);                  \
        int t_ = pos2tok[base + ii];                             \
        const float4* r_ = encb + (size_t)t_ * (Hdim / 4);       \
        v0 = r_[lane]; v1 = r_[lane + 64]; v2 = r_[lane + 128];  \
      }
#define PROCROW(v0, v1, v2, SLOT)                                      \
      {                                                                \
        float dd[3];                                                   \
        _Pragma("unroll") for (int c = 0; c < 3; ++c) if (c < nc) {    \
          dd[c] = v0.x * wf[0][0][c] + v0.y * wf[0][1][c] +            \
                  v0.z * wf[0][2][c] + v0.w * wf[0][3][c] +            \
                  v1.x * wf[1][0][c] + v1.y * wf[1][1][c] +            \
                  v1.z * wf[1][2][c] + v1.w * wf[1][3][c] +            \
                  v2.x * wf[2][0][c] + v2.y * wf[2][1][c] +            \
                  v2.z * wf[2][2][c] + v2.w * wf[2][3][c];             \
          dd[c] = wave_sum63(dd[c]);                                   \
        }                                                              \
        if (lane == 63) {                                              \
          float* dst = proj + (size_t)(base + (SLOT)) * PSTRIDE + l0;  \
          _Pragma("unroll") for (int c = 0; c < 3; ++c)                \
            if (c < nc) dst[c] = dd[c];                                \
        }                                                              \
      }
      LDROW(xa0, xa1, xa2, 0)
      LDROW(xb0, xb1, xb2, 1)
      for (int i = 0; i < vc; i += 2) {
        PROCROW(xa0, xa1, xa2, i)
        LDROW(xa0, xa1, xa2, i + 2)   // refill for iteration i+2
        if (i + 1 < vc) PROCROW(xb0, xb1, xb2, i + 1)
        LDROW(xb0, xb1, xb2, i + 3)
      }
#undef LDROW
#undef PROCROW
    }
  }
  grid.sync();

  // ================= phase 3: words (100 per block) =================
  {
    float nll = 0.0f, cnt = 0.0f;
    if (tid < WPB) {
      int bs = blk * WPB + tid;
      int b2 = bs / Sdim;
      int len = ids_lens[bs];
      float sum[Ldim];
#pragma unroll
      for (int l = 0; l < Ldim; ++l) sum[l] = 0.0f;
      if (len > 0) {
        int start = wstart[bs];
        int nv2 = nvalid[b2];
        for (int j = 0; j < len; ++j) {
          int q = start + j;
          if (q >= nv2) break;
          const float* prow = proj + ((size_t)(b2 << 9) + q) * PSTRIDE;
#pragma unroll
          for (int l = 0; l < Ldim; ++l) sum[l] += prow[l];
        }
      }
      float inv = (len > 0) ? 1.0f / (float)len : 0.0f;
      float lg[Ldim];
#pragma unroll
      for (int l = 0; l < Ldim; ++l) lg[l] = sum[l] * inv + bias[l];
      int amax = 0;
      float mx = lg[0];
#pragma unroll
      for (int l = 1; l < Ldim; ++l)
        if (lg[l] > mx) { mx = lg[l]; amax = l; }
      out[1 + bs] = (float)amax;
      if (len > 0) {
        float se = 0.0f;
#pragma unroll
        for (int l = 0; l < Ldim; ++l) se += expf(lg[l] - mx);
        float lse = mx + logf(se);
        int lab = label_ids[bs];
        float ll = lg[0];
#pragma unroll
        for (int l = 1; l < Ldim; ++l) ll = (lab == l) ? lg[l] : ll;
        nll = lse - ll;
        cnt = 1.0f;
      }
    }
#pragma unroll
    for (int off = 32; off > 0; off >>= 1) {
      nll += __shfl_down(nll, off, 64);
      cnt += __shfl_down(cnt, off, 64);
    }
    if (lane == 0) { ssm[w] = nll; csm[w] = cnt; }
    __syncthreads();
    if (tid == 0) {
      float2 pc;
      pc.x = ssm[0] + ssm[1] + ssm[2] + ssm[3];
      pc.y = csm[0] + csm[1] + csm[2] + csm[3];
      partials[blk] = pc;
    }
  }
  grid.sync();

  // ================= phase 4: final loss (block 0) =================
  if (blk == 0) {
    float2 pc = partials[tid];  // NBLK == NTHR == 256
    float s = pc.x, c = pc.y;
#pragma unroll
    for (int off = 32; off > 0; off >>= 1) {
      s += __shfl_down(s, off, 64);
      c += __shfl_down(c, off, 64);
    }
    if (lane == 0) { ssm[w] = s; csm[w] = c; }
    __syncthreads();
    if (tid == 0)
      out[0] = (ssm[0] + ssm[1] + ssm[2] + ssm[3]) /
               (csm[0] + csm[1] + csm[2] + csm[3]);
  }
}

extern "C" void kernel_launch(void* const* d_in, const int* in_sizes, int n_in,
                              void* d_out, int out_size, void* d_ws, size_t ws_size,
                              hipStream_t stream) {
  const float* enc     = (const float*)d_in[0];  // [B,T,H] f32
  const float* W       = (const float*)d_in[1];  // [H,L]   f32
  const float* bias    = (const float*)d_in[2];  // [L]     f32
  const int* attn      = (const int*)d_in[3];    // [B,T]   i32
  const int* ids_lens  = (const int*)d_in[4];    // [B,S]   i32
  const int* label_ids = (const int*)d_in[5];    // [B,S]   i32
  // d_in[6] label_mask is recomputed from ids_lens>0

  float* out = (float*)d_out;  // [1 + B*S]: loss, then argmax as float

  char* ws = (char*)d_ws;
  size_t off0 = 0;
  int* pos2tok     = (int*)(ws + off0);    off0 += (size_t)Bdim * Tdim * sizeof(int);
  int* wstart      = (int*)(ws + off0);    off0 += (size_t)Bdim * Sdim * sizeof(int);
  int* nvalid      = (int*)(ws + off0);    off0 += 256;
  float* proj      = (float*)(ws + off0);  off0 += (size_t)Bdim * Tdim * PSTRIDE * sizeof(float);
  float2* partials = (float2*)(ws + off0); off0 += NBLK * sizeof(float2);

  void* args[] = {(void*)&enc,      (void*)&W,      (void*)&bias,
                  (void*)&attn,     (void*)&ids_lens, (void*)&label_ids,
                  (void*)&pos2tok,  (void*)&wstart, (void*)&nvalid,
                  (void*)&proj,     (void*)&partials, (void*)&out};
  hipLaunchCooperativeKernel((void*)fused_kernel, dim3(NBLK), dim3(NTHR),
                             args, 0, stream);
}

// Round 9
// 34.576 us; speedup vs baseline: 4.3023x; 4.3023x over previous
//
#include <hip/hip_runtime.h>
#include <math.h>

#define Bdim 64
#define Tdim 512
#define Sdim 400
#define Hdim 768
#define Ldim 9
#define PSTRIDE 12  // padded proj row stride (16B-aligned)

#define PROJ_BLOCKS 2048
#define ROWS_PER_BLK 16  // 2048 * 16 = 32768 = B*T rows, ALL projected

// ---------------------------------------------------------------------------
// DPP 64-lane sum (row_shr 1/2/4/8 + row_bcast 15/31), result in lane 63.
// Pure VALU, no DS pipe.
// ---------------------------------------------------------------------------
template <int CTRL>
__device__ __forceinline__ float dpp_add(float x) {
  int y = __builtin_amdgcn_update_dpp(0, __float_as_int(x), CTRL, 0xF, 0xF, false);
  return x + __int_as_float(y);
}
__device__ __forceinline__ float wave_sum63(float x) {
  x = dpp_add<0x111>(x);
  x = dpp_add<0x112>(x);
  x = dpp_add<0x114>(x);
  x = dpp_add<0x118>(x);
  x = dpp_add<0x142>(x);
  x = dpp_add<0x143>(x);
  return x;  // lane 63 = sum of all 64 lanes
}

// ---------------------------------------------------------------------------
// Kernel 1: STREAMING projection of ALL 32768 token rows (no gather, no
// setup dependency, perfect balance -- R8 showed the gathered/imbalanced
// variant is the dominant cost; pads' projections are never read later).
// Block = 192 threads = 3 waves; wave w computes logits {3w..3w+2} with a
// 36-float register W fragment (R5: 108-float fragments get silently
// rematerialized -- VGPR=80 tell). Depth-2 ping-pong prefetch.
// Block 0 also zeroes the loss accumulators (ws is not re-poisoned).
// ---------------------------------------------------------------------------
__global__ __launch_bounds__(192, 4) void proj_kernel(
    const float* __restrict__ enc, const float* __restrict__ W,
    float* __restrict__ proj, float* __restrict__ accum,
    unsigned* __restrict__ counter) {
  int tid = threadIdx.x;
  int lane = tid & 63;
  int w = tid >> 6;   // 0..2
  int l0 = w * 3;     // logit slice {l0, l0+1, l0+2}
  int base = blockIdx.x * ROWS_PER_BLK;

  if (blockIdx.x == 0) {
    if (tid < 2) accum[tid] = 0.0f;
    if (tid == 2) *counter = 0u;
  }

  // per-lane W fragment: h = 4*lane + 256*k + j (k<3, j<4), cols l0..l0+2
  float wf[3][4][3];
#pragma unroll
  for (int k = 0; k < 3; ++k)
#pragma unroll
    for (int j = 0; j < 4; ++j) {
      int h = 4 * lane + 256 * k + j;
#pragma unroll
      for (int c = 0; c < 3; ++c) wf[k][j][c] = W[(size_t)h * Ldim + l0 + c];
    }

  const float4* encf4 = (const float4*)enc;  // row p at p*(Hdim/4)

  float4 xa0, xa1, xa2, xb0, xb1, xb2;
#define LDROW(v0, v1, v2, IDX)                                             \
  {                                                                        \
    const float4* r_ = encf4 + (size_t)(base + (IDX)) * (Hdim / 4);        \
    v0 = r_[lane]; v1 = r_[lane + 64]; v2 = r_[lane + 128];                \
  }
#define PROCROW(v0, v1, v2, IDX)                                           \
  {                                                                        \
    float dd[3];                                                           \
    _Pragma("unroll") for (int c = 0; c < 3; ++c) {                        \
      dd[c] = v0.x * wf[0][0][c] + v0.y * wf[0][1][c] +                    \
              v0.z * wf[0][2][c] + v0.w * wf[0][3][c] +                    \
              v1.x * wf[1][0][c] + v1.y * wf[1][1][c] +                    \
              v1.z * wf[1][2][c] + v1.w * wf[1][3][c] +                    \
              v2.x * wf[2][0][c] + v2.y * wf[2][1][c] +                    \
              v2.z * wf[2][2][c] + v2.w * wf[2][3][c];                     \
      dd[c] = wave_sum63(dd[c]);                                           \
    }                                                                      \
    if (lane == 63) {                                                      \
      float* dst = proj + (size_t)(base + (IDX)) * PSTRIDE + l0;           \
      dst[0] = dd[0]; dst[1] = dd[1]; dst[2] = dd[2];                      \
    }                                                                      \
  }

  LDROW(xa0, xa1, xa2, 0)
  LDROW(xb0, xb1, xb2, 1)
#pragma unroll
  for (int i = 0; i < ROWS_PER_BLK; i += 2) {
    PROCROW(xa0, xa1, xa2, i)
    if (i + 2 < ROWS_PER_BLK) LDROW(xa0, xa1, xa2, i + 2)
    PROCROW(xb0, xb1, xb2, i + 1)
    if (i + 3 < ROWS_PER_BLK) LDROW(xb0, xb1, xb2, i + 3)
  }
#undef LDROW
#undef PROCROW
}

// ---------------------------------------------------------------------------
// Kernel 2: one block per batch row (512 threads, 8 waves).
//  phase A: scans of attn (-> pos2tok in LDS) and ids_lens (-> wstart in
//           LDS, len kept in register) -- no global index buffers at all
//  phase B: thread s<400 handles word s: mean of its tokens' proj rows
//           (L2-resident), +bias, argmax -> out, NLL partial
//  phase C: block reduce; 64 block-atomics; last block finalizes loss.
// ---------------------------------------------------------------------------
__global__ __launch_bounds__(Tdim) void rowword_kernel(
    const float* __restrict__ proj, const float* __restrict__ bias,
    const int* __restrict__ attn, const int* __restrict__ ids_lens,
    const int* __restrict__ label_ids, float* __restrict__ out,
    float* __restrict__ accum, unsigned* __restrict__ counter) {
  int b = blockIdx.x;
  int tid = threadIdx.x;
  int lane = tid & 63, wid = tid >> 6;
  __shared__ int p2t[Tdim];
  __shared__ int wst[Sdim];
  __shared__ int wsum[8];
  __shared__ int totsm;
  __shared__ float ssm[8], csm[8];

  // ---- scan 1: attention mask -> p2t (LDS), nvalid ----
  int m = attn[b * Tdim + tid];
  int x = m;
#pragma unroll
  for (int off = 1; off < 64; off <<= 1) {
    int v = __shfl_up(x, off, 64);
    if (lane >= off) x += v;
  }
  if (lane == 63) wsum[wid] = x;
  __syncthreads();
  if (tid < 8) {
    int s = wsum[tid], y = s;
#pragma unroll
    for (int off = 1; off < 8; off <<= 1) {
      int v = __shfl_up(y, off, 64);
      if (tid >= off) y += v;
    }
    wsum[tid] = y - s;
    if (tid == 7) totsm = y;
  }
  __syncthreads();
  x += wsum[wid];
  if (m) p2t[x - 1] = tid;  // q-th valid token -> position tid
  int nv_local = totsm;
  __syncthreads();  // p2t fully written; wsum reusable

  // ---- scan 2: ids_lens -> wstart (LDS); len stays in register ----
  int len = (tid < Sdim) ? ids_lens[b * Sdim + tid] : 0;
  int x2 = len;
#pragma unroll
  for (int off = 1; off < 64; off <<= 1) {
    int v = __shfl_up(x2, off, 64);
    if (lane >= off) x2 += v;
  }
  if (lane == 63) wsum[wid] = x2;
  __syncthreads();
  if (tid < 8) {
    int s = wsum[tid], y = s;
#pragma unroll
    for (int off = 1; off < 8; off <<= 1) {
      int v = __shfl_up(y, off, 64);
      if (tid >= off) y += v;
    }
    wsum[tid] = y - s;
  }
  __syncthreads();
  x2 += wsum[wid];
  if (tid < Sdim) wst[tid] = x2 - len;  // exclusive prefix
  __syncthreads();

  // ---- phase B: words ----
  float nll = 0.0f, cnt = 0.0f;
  if (tid < Sdim) {
    int bs = b * Sdim + tid;
    float sum[Ldim];
#pragma unroll
    for (int l = 0; l < Ldim; ++l) sum[l] = 0.0f;
    if (len > 0) {
      int start = wst[tid];
      for (int j = 0; j < len; ++j) {
        int q = start + j;
        if (q >= nv_local) break;
        const float* pr = proj + ((size_t)(b << 9) + p2t[q]) * PSTRIDE;
        const float4* pr4 = (const float4*)pr;
        float4 r0 = pr4[0], r1 = pr4[1];
        float r8 = pr[8];
        sum[0] += r0.x; sum[1] += r0.y; sum[2] += r0.z; sum[3] += r0.w;
        sum[4] += r1.x; sum[5] += r1.y; sum[6] += r1.z; sum[7] += r1.w;
        sum[8] += r8;
      }
    }
    float inv = (len > 0) ? 1.0f / (float)len : 0.0f;
    float lg[Ldim];
#pragma unroll
    for (int l = 0; l < Ldim; ++l) lg[l] = sum[l] * inv + bias[l];

    int amax = 0;
    float mx = lg[0];
#pragma unroll
    for (int l = 1; l < Ldim; ++l)
      if (lg[l] > mx) { mx = lg[l]; amax = l; }
    out[1 + bs] = (float)amax;

    if (len > 0) {
      float se = 0.0f;
#pragma unroll
      for (int l = 0; l < Ldim; ++l) se += expf(lg[l] - mx);
      float lse = mx + logf(se);
      int lab = label_ids[bs];
      float ll = lg[0];
#pragma unroll
      for (int l = 1; l < Ldim; ++l) ll = (lab == l) ? lg[l] : ll;
      nll = lse - ll;
      cnt = 1.0f;
    }
  }

  // ---- phase C: block reduce + finalize ----
#pragma unroll
  for (int off = 32; off > 0; off >>= 1) {
    nll += __shfl_down(nll, off, 64);
    cnt += __shfl_down(cnt, off, 64);
  }
  if (lane == 0) { ssm[wid] = nll; csm[wid] = cnt; }
  __syncthreads();
  if (tid == 0) {
    float S = 0.f, C = 0.f;
#pragma unroll
    for (int k = 0; k < 8; ++k) { S += ssm[k]; C += csm[k]; }
    atomicAdd(&accum[0], S);
    atomicAdd(&accum[1], C);
    __threadfence();
    unsigned prev = atomicAdd(counter, 1u);
    if (prev == gridDim.x - 1) {
      __threadfence();
      float Sf = atomicAdd(&accum[0], 0.0f);
      float Cf = atomicAdd(&accum[1], 0.0f);
      out[0] = Sf / Cf;
    }
  }
}

extern "C" void kernel_launch(void* const* d_in, const int* in_sizes, int n_in,
                              void* d_out, int out_size, void* d_ws, size_t ws_size,
                              hipStream_t stream) {
  const float* enc     = (const float*)d_in[0];  // [B,T,H] f32
  const float* W       = (const float*)d_in[1];  // [H,L]   f32
  const float* bias    = (const float*)d_in[2];  // [L]     f32
  const int* attn      = (const int*)d_in[3];    // [B,T]   i32
  const int* ids_lens  = (const int*)d_in[4];    // [B,S]   i32
  const int* label_ids = (const int*)d_in[5];    // [B,S]   i32
  // d_in[6] label_mask is recomputed from ids_lens>0

  float* out = (float*)d_out;  // [1 + B*S]: loss, then argmax as float

  char* ws = (char*)d_ws;
  size_t off0 = 0;
  float* accum      = (float*)(ws + off0);    off0 += 128;
  unsigned* counter = (unsigned*)(ws + off0); off0 += 128;
  float* proj       = (float*)(ws + off0);    off0 += (size_t)Bdim * Tdim * PSTRIDE * sizeof(float);

  proj_kernel<<<PROJ_BLOCKS, 192, 0, stream>>>(enc, W, proj, accum, counter);
  rowword_kernel<<<Bdim, Tdim, 0, stream>>>(proj, bias, attn, ids_lens,
                                            label_ids, out, accum, counter);
}